// Round 5
// baseline (607.593 us; speedup 1.0000x reference)
//
#include <hip/hip_runtime.h>

// Round 5: batch-major pipeline. h-packed activation layouts (ushort4) so
// k5/k6 convs get all h-taps per 8B load; k6 o-tile widened to 64 with
// compile-time H3 specialization. Tail folded via atomics (round 4).

typedef unsigned short u16;

__device__ __forceinline__ float bf2f(u16 u) {
  return __uint_as_float(((unsigned)u) << 16);
}
__device__ __forceinline__ u16 f2bf(float f) {
  unsigned u = __float_as_uint(f);
  return (u16)((u + 0x7FFFu + ((u >> 16) & 1u)) >> 16);   // RNE
}

// ---- fp32 ws region offsets (floats) ----
#define OF_CS01   0        // 81
#define OF_CS1    81       // 30
#define OF_CSR    111      // 30
#define OF_CSAC   141      // 125
#define OF_CS02   266      // 10
#define OF_CSCC2  276      // 1
#define OF_L01T   277      // 127*81
#define OF_R01T   10564    // 127*81
#define OF_SWT    20851    // 81*60
#define OF_CB1T   25711    // 15*25  [k=c5*3+dh][c]
#define OF_C1T    26086    // 50*75  [k=c*2+dc][m]
#define OF_C2T    29836    // 150*128 [k=m*2+dc][o pad 128]
#define OF_CAT    49036    // 75*128  [k=c*3+dc3][o pad 128]
#define OF_SCT    58636    // 30*20
#define OF_CA2T   59236    // 250*25
#define F32_TOTAL 65486

// ---- activation pool (u16 rows, pitch CB), lifetimes overlapped ----
#define R_XT   0      // 635   [K0T..K1]
#define R_XL   635    // 405   [K1..K2]
#define R_YA   1040   // 405   [K1..K3]
#define R_ZA   1445   // 2025  [K2..K3]
#define R_P    3470   // 1500  [K3..K4]
#define R_Q    4970   // 300   [K3..K4]
#define R_X2   0      // 11250 [K6..K7]  (reuses 0..5270 dead region + slack)
#define R_V4A  11250  // 6000  (1500 ushort4-rows) [K4..K6]
#define R_V1   17250  // 1500  [K4..K6]
#define R_T8   18750  // 9000  (2250 ushort4-rows) [K5..K6]
#define R_XJ   11250  // 3750  [K7..K8a] (reuses v4a)
#define ROWS_TOTAL 27750

struct Ctx {
  const float *x, *ca1_w, *ca1_b, *l01_b, *r01_b, *cb1_b, *cc1_w, *cc1_b;
  const float *c1_b, *l1_b, *c2_b, *ca_b, *ra_b, *ca2_b, *l02_b;
  const float *cb2_w, *cb2_b, *cc2_w, *cc2_b, *r02_b, *fl_w, *fl_b;
  const float *l01_w, *r01_w, *l1_w, *ra_w, *c1_w, *c2_w, *ca_w, *cb1_w;
  const float *l02_w, *r02_w, *ca2_w;
  float *F;
  float *zAcc;      // [CB]
  float *yAcc;      // [3][CB]
  u16 *A;
  float *out;
  int CB;
  int b0g;
};

// ---------- K0C: constants + transposed weights. grid(32) ----------
__global__ __launch_bounds__(256) void k0c(Ctx C) {
  const int t0 = blockIdx.x * 256 + threadIdx.x;
  const int NT = 32 * 256;
  float* F = C.F;
  for (int k = t0; k < 277; k += NT) {
    float s = 0.f;
    if (k < 81)       { for (int i = 0; i < 127; ++i) s += C.l01_w[k * 127 + i]; F[OF_CS01 + k] = s; }
    else if (k < 111) { int j = k - 81;  for (int a = 0; a < 81; ++a) s += C.l1_w[j * 81 + a]; F[OF_CS1 + j] = s; }
    else if (k < 141) { int j = k - 111; for (int a = 0; a < 81; ++a) s += C.ra_w[j * 81 + a]; F[OF_CSR + j] = s; }
    else if (k < 266) { int o = k - 141; for (int i = 0; i < 75; ++i) s += C.ca_w[o * 75 + i]; F[OF_CSAC + o] = s; }
    else if (k < 276) { int q = k - 266; for (int j = 0; j < 30; ++j) s += C.l02_w[q * 30 + j]; F[OF_CS02 + q] = s; }
    else              { float ss = 0.f; for (int o = 0; o < 125; ++o) ss += C.cc2_w[o]; F[OF_CSCC2] = ss; }
  }
  for (int e = t0; e < 10287; e += NT) { int i = e / 81, a = e % 81; F[OF_L01T + e] = C.l01_w[a * 127 + i]; }
  for (int e = t0; e < 10287; e += NT) { int i = e / 81, a = e % 81; F[OF_R01T + e] = C.r01_w[a * 127 + i]; }
  for (int e = t0; e < 4860; e += NT)  { int a = e / 60, j2 = e % 60;
    F[OF_SWT + e] = (j2 < 30) ? C.l1_w[j2 * 81 + a] : C.ra_w[(j2 - 30) * 81 + a]; }
  for (int e = t0; e < 375; e += NT)   { int k = e / 25, c = e % 25; F[OF_CB1T + e] = C.cb1_w[c * 15 + k]; }
  for (int e = t0; e < 3750; e += NT)  { int k = e / 75, m = e % 75; F[OF_C1T + e] = C.c1_w[m * 50 + k]; }
  for (int e = t0; e < 19200; e += NT) { int k = e / 128, o = e % 128;
    F[OF_C2T + e] = (o < 125) ? C.c2_w[o * 150 + k] : 0.f; }
  for (int e = t0; e < 9600; e += NT)  { int k = e / 128, o = e % 128;
    F[OF_CAT + e] = (o < 125) ? C.ca_w[o * 75 + k] : 0.f; }
  for (int e = t0; e < 600; e += NT)   { int j = e / 20, q2 = e % 20;
    F[OF_SCT + e] = (q2 < 10) ? C.l02_w[q2 * 30 + j] : C.r02_w[(q2 - 10) * 30 + j]; }
  for (int e = t0; e < 6250; e += NT)  { int k = e / 25, c = e % 25; F[OF_CA2T + e] = C.ca2_w[c * 250 + k]; }
}

// ---------- K0T: transpose x -> xT[635][CB] bf16. grid (CB/64, 10) ----------
__global__ __launch_bounds__(256) void k0t(Ctx C) {
  __shared__ float tile[64][65];
  const int tid = threadIdx.x;
  const int b0 = blockIdx.x * 64;
  const int i0 = blockIdx.y * 64;
  for (int e = tid; e < 64 * 64; e += 256) {
    int s = e >> 6, ii = e & 63, gi = i0 + ii;
    if (gi < 635) tile[s][ii] = C.x[(size_t)(C.b0g + b0 + s) * 635 + gi];
  }
  __syncthreads();
  const int lane = tid & 63, wv = tid >> 6;
  u16* xT = C.A + (size_t)R_XT * C.CB;
#pragma unroll
  for (int k = 0; k < 16; ++k) {
    int r = wv * 16 + k, gi = i0 + r;
    if (gi < 635) xT[(size_t)gi * C.CB + b0 + lane] = f2bf(tile[lane][r]);
  }
}

// ---------- K1: XL = l01*x, yA = r01*x + r01_b. grid (CB/256, 30) ----------
__global__ __launch_bounds__(256) void k1(Ctx C) {
  const int col = blockIdx.x * 256 + threadIdx.x;
  if (col >= C.CB) return;
  const int g = blockIdx.y, type = g / 15, r = g % 15, h = r / 3, a0 = (r % 3) * 27;
  const u16* __restrict__ xT = C.A + (size_t)R_XT * C.CB;
  const float* __restrict__ wT = C.F + (type ? OF_R01T : OF_L01T) + a0;
  float acc[27];
#pragma unroll
  for (int a = 0; a < 27; ++a) acc[a] = 0.f;
  for (int i = 0; i < 127; ++i) {
    float xv = bf2f(xT[(size_t)(h * 127 + i) * C.CB + col]);
    const float* __restrict__ w = wT + i * 81;
#pragma unroll
    for (int a = 0; a < 27; ++a) acc[a] += w[a] * xv;
  }
  u16* dst = C.A + (size_t)(type ? R_YA : R_XL) * C.CB;
#pragma unroll
  for (int a = 0; a < 27; ++a) {
    float rr = acc[a] + (type ? C.r01_b[a0 + a] : 0.f);
    dst[(size_t)(h * 81 + a0 + a) * C.CB + col] = f2bf(rr);
  }
}

// ---------- K2: zA = relu(conv_ca1(XL) + ca1_b*S01 + l01_b). grid (CB/256, 75) ----------
__global__ __launch_bounds__(256) void k2(Ctx C) {
  const int col = blockIdx.x * 256 + threadIdx.x;
  if (col >= C.CB) return;
  const int g = blockIdx.y, c5 = g / 15, r = g % 15, h = r / 3, a0 = (r % 3) * 27;
  const u16* __restrict__ XL = C.A + (size_t)R_XL * C.CB;
  const float* __restrict__ F = C.F;
  float acc[27];
  float cb = C.ca1_b[c5];
#pragma unroll
  for (int a = 0; a < 27; ++a) acc[a] = cb * F[OF_CS01 + a0 + a] + C.l01_b[a0 + a];
  for (int dh = 0; dh < 3; ++dh) {
    int hp = h - 1 + dh;
    if (hp < 0 || hp > 4) continue;
    float w = C.ca1_w[c5 * 3 + dh];
#pragma unroll
    for (int a = 0; a < 27; ++a) acc[a] += w * bf2f(XL[(size_t)(hp * 81 + a0 + a) * C.CB + col]);
  }
  u16* zA = C.A + (size_t)R_ZA * C.CB;
#pragma unroll
  for (int a = 0; a < 27; ++a)
    zA[(size_t)((c5 * 5 + h) * 81 + a0 + a) * C.CB + col] = f2bf(fmaxf(acc[a], 0.f));
}

// ---------- K3: P = SW*zA, Q = SW*yA. grid (CB/256, 60) ----------
__global__ __launch_bounds__(256) void k3(Ctx C) {
  const int col = blockIdx.x * 256 + threadIdx.x;
  if (col >= C.CB) return;
  const int g = blockIdx.y, pair = g >> 1, j0 = (g & 1) * 30;
  const bool isP = (pair < 25);
  const u16* __restrict__ src = C.A + (size_t)(isP ? (R_ZA + pair * 81) : (R_YA + (pair - 25) * 81)) * C.CB;
  const float* __restrict__ SWT = C.F + OF_SWT + j0;
  float acc[30];
#pragma unroll
  for (int j = 0; j < 30; ++j) acc[j] = 0.f;
  for (int a = 0; a < 81; ++a) {
    float xv = bf2f(src[(size_t)a * C.CB + col]);
    const float* __restrict__ w = SWT + a * 60;
#pragma unroll
    for (int j = 0; j < 30; ++j) acc[j] += w[j] * xv;
  }
  u16* dst = C.A + (size_t)(isP ? (R_P + pair * 60) : (R_Q + (pair - 25) * 60)) * C.CB;
#pragma unroll
  for (int j = 0; j < 30; ++j) dst[(size_t)(j0 + j) * C.CB + col] = f2bf(acc[j]);
}

// ---------- K4: v packed. thread=(cg,j2), acc[5c][5h]. grid (CB/256, 300) ----------
__global__ __launch_bounds__(256) void k4(Ctx C) {
  const int col = blockIdx.x * 256 + threadIdx.x;
  if (col >= C.CB) return;
  const int g = blockIdx.y, cg = g / 60, j2 = g % 60;
  const u16* __restrict__ Pb = C.A + (size_t)R_P * C.CB;
  const u16* __restrict__ Qb = C.A + (size_t)R_Q * C.CB;
  const float* __restrict__ F = C.F;
  float sj = (j2 < 30) ? F[OF_CS1 + j2] : F[OF_CSR + (j2 - 30)];
  float acc[5][5];
#pragma unroll
  for (int cl = 0; cl < 5; ++cl) {
    int c = cg * 5 + cl;
    float base = (C.cb1_b[c] + C.cc1_b[c]) * sj;
    float cw = C.cc1_w[c];
#pragma unroll
    for (int h = 0; h < 5; ++h)
      acc[cl][h] = base + cw * bf2f(Qb[(size_t)(h * 60 + j2) * C.CB + col]);
  }
#pragma unroll
  for (int c5 = 0; c5 < 5; ++c5)
#pragma unroll
    for (int hp = 0; hp < 5; ++hp) {
      float pv = bf2f(Pb[(size_t)((c5 * 5 + hp) * 60 + j2) * C.CB + col]);
#pragma unroll
      for (int dh = 0; dh < 3; ++dh) {
        int h = hp + 1 - dh;
        if (h < 0 || h > 4) continue;
        const float* __restrict__ w = F + OF_CB1T + (c5 * 3 + dh) * 25 + cg * 5;
#pragma unroll
        for (int cl = 0; cl < 5; ++cl) acc[cl][h] += w[cl] * pv;
      }
    }
  u16* v4 = C.A + (size_t)R_V4A * C.CB;
  u16* v1 = C.A + (size_t)R_V1 * C.CB;
#pragma unroll
  for (int cl = 0; cl < 5; ++cl) {
    int row = (cg * 5 + cl) * 60 + j2;
    ushort4 pk;
    pk.x = f2bf(acc[cl][0]); pk.y = f2bf(acc[cl][1]);
    pk.z = f2bf(acc[cl][2]); pk.w = f2bf(acc[cl][3]);
    *(ushort4*)(v4 + ((size_t)row * C.CB + col) * 4) = pk;
    v1[(size_t)row * C.CB + col] = f2bf(acc[cl][4]);
  }
}

// ---------- K5: t packed. thread=(mg,j), acc[15m][4h]. grid (CB/256, 150) ----------
__global__ __launch_bounds__(256) void k5(Ctx C) {
  const int col = blockIdx.x * 256 + threadIdx.x;
  if (col >= C.CB) return;
  const int g = blockIdx.y, mg = g / 30, j = g % 30;
  const u16* __restrict__ v4 = C.A + (size_t)R_V4A * C.CB;
  const u16* __restrict__ v1 = C.A + (size_t)R_V1 * C.CB;
  const float* __restrict__ F = C.F;
  float acc[15][4];
  float s1 = F[OF_CS1 + j], lb = C.l1_b[j];
#pragma unroll
  for (int ml = 0; ml < 15; ++ml) {
    float bb = C.c1_b[mg * 15 + ml] * s1 + lb;
#pragma unroll
    for (int h = 0; h < 4; ++h) acc[ml][h] = bb;
  }
  for (int c = 0; c < 25; ++c) {
    int row = c * 60 + j;
    ushort4 pk = *(const ushort4*)(v4 + ((size_t)row * C.CB + col) * 4);
    float vals[5];
    vals[0] = bf2f(pk.x); vals[1] = bf2f(pk.y); vals[2] = bf2f(pk.z); vals[3] = bf2f(pk.w);
    vals[4] = bf2f(v1[(size_t)row * C.CB + col]);
#pragma unroll
    for (int dc = 0; dc < 2; ++dc) {
      const float* __restrict__ w = F + OF_C1T + (c * 2 + dc) * 75 + mg * 15;
#pragma unroll
      for (int ml = 0; ml < 15; ++ml) {
        float wv = w[ml];
        acc[ml][0] += wv * vals[0 + dc];
        acc[ml][1] += wv * vals[1 + dc];
        acc[ml][2] += wv * vals[2 + dc];
        acc[ml][3] += wv * vals[3 + dc];
      }
    }
  }
  u16* t8 = C.A + (size_t)R_T8 * C.CB;
#pragma unroll
  for (int ml = 0; ml < 15; ++ml) {
    int row = (mg * 15 + ml) * 30 + j;
    ushort4 pk;
    pk.x = f2bf(fmaxf(acc[ml][0], 0.f)); pk.y = f2bf(fmaxf(acc[ml][1], 0.f));
    pk.z = f2bf(fmaxf(acc[ml][2], 0.f)); pk.w = f2bf(fmaxf(acc[ml][3], 0.f));
    *(ushort4*)(t8 + ((size_t)row * C.CB + col) * 4) = pk;
  }
}

// ---------- K6<H3>: x2 = conv_c2(t) + conv_ca(vR) + bias. o-tile 64. grid (CB/256, 60) ----------
template <int H3>
__global__ __launch_bounds__(256) void k6t(Ctx C) {
  const int col = blockIdx.x * 256 + threadIdx.x;
  if (col >= C.CB) return;
  const int g = blockIdx.y;
  const int ot = g & 1, j = g >> 1;          // ot fastest: both o-tiles of a j adjacent
  const int ow = ot * 64;
  const u16* __restrict__ t8 = C.A + (size_t)R_T8 * C.CB;
  const u16* __restrict__ v4 = C.A + (size_t)R_V4A * C.CB;
  const u16* __restrict__ v1 = C.A + (size_t)R_V1 * C.CB;
  const float* __restrict__ F = C.F;
  float acc[64];
#pragma unroll
  for (int i = 0; i < 64; ++i) acc[i] = 0.f;

  for (int m = 0; m < 75; ++m) {
    int row = m * 30 + j;
    ushort4 pk = *(const ushort4*)(t8 + ((size_t)row * C.CB + col) * 4);
    float t0, t1;
    if constexpr (H3 == 0)      { t0 = bf2f(pk.x); t1 = bf2f(pk.y); }
    else if constexpr (H3 == 1) { t0 = bf2f(pk.y); t1 = bf2f(pk.z); }
    else                        { t0 = bf2f(pk.z); t1 = bf2f(pk.w); }
    const float* __restrict__ w0 = F + OF_C2T + (2 * m) * 128 + ow;
    const float* __restrict__ w1 = w0 + 128;
#pragma unroll
    for (int i = 0; i < 64; ++i) acc[i] += w0[i] * t0 + w1[i] * t1;
  }
  for (int c = 0; c < 25; ++c) {
    int row = c * 60 + 30 + j;
    ushort4 pk = *(const ushort4*)(v4 + ((size_t)row * C.CB + col) * 4);
    float a0, a1, a2;
    if constexpr (H3 == 0)      { a0 = bf2f(pk.x); a1 = bf2f(pk.y); a2 = bf2f(pk.z); }
    else if constexpr (H3 == 1) { a0 = bf2f(pk.y); a1 = bf2f(pk.z); a2 = bf2f(pk.w); }
    else                        { a0 = bf2f(pk.z); a1 = bf2f(pk.w);
                                  a2 = bf2f(v1[(size_t)row * C.CB + col]); }
    const float* __restrict__ wa = F + OF_CAT + (c * 3) * 128 + ow;
#pragma unroll
    for (int i = 0; i < 64; ++i)
      acc[i] += wa[i] * a0 + wa[128 + i] * a1 + wa[256 + i] * a2;
  }
  u16* x2b = C.A + (size_t)R_X2 * C.CB;
  float rbj = C.ra_b[j];
#pragma unroll
  for (int i = 0; i < 64; ++i) {
    int o = ow + i;
    if (o < 125) {
      float rr = acc[i] + C.c2_b[o] + C.ca_b[o] + rbj * F[OF_CSAC + o];
      x2b[(size_t)((o * 3 + H3) * 30 + j) * C.CB + col] = f2bf(rr);
    }
  }
}

// ---------- K7: XJ_left = SC_l * x2; fold right half into yAcc. grid (CB/256, 375) ----------
__global__ __launch_bounds__(256) void k7(Ctx C) {
  const int col = blockIdx.x * 256 + threadIdx.x;
  if (col >= C.CB) return;
  const int g = blockIdx.y;               // g = o*3 + h3
  const int o = g / 3, h3 = g % 3;
  const u16* __restrict__ x2b = C.A + (size_t)R_X2 * C.CB;
  const float* __restrict__ SCT = C.F + OF_SCT;
  float acc[20];
#pragma unroll
  for (int q = 0; q < 20; ++q) acc[q] = 0.f;
  for (int j = 0; j < 30; ++j) {
    float xv = bf2f(x2b[(size_t)(g * 30 + j) * C.CB + col]);
    const float* __restrict__ w = SCT + j * 20;
#pragma unroll
    for (int q = 0; q < 20; ++q) acc[q] += w[q] * xv;
  }
  u16* XJ = C.A + (size_t)R_XJ * C.CB;
#pragma unroll
  for (int q = 0; q < 10; ++q) XJ[(size_t)(g * 10 + q) * C.CB + col] = f2bf(acc[q]);
  float s = 0.f;
#pragma unroll
  for (int q = 0; q < 10; ++q) s += C.fl_w[q] * acc[10 + q];
  atomicAdd(&C.yAcc[(size_t)h3 * C.CB + col], C.cc2_w[o] * s);
}

// ---------- K8a: zC in regs; fold cb2+fl into zAcc. grid (CB/256, 20) ----------
__global__ __launch_bounds__(256) void k8a(Ctx C) {
  const int col = blockIdx.x * 256 + threadIdx.x;
  if (col >= C.CB) return;
  const int g = blockIdx.y, hh = g / 10, q = g % 10;
  const u16* __restrict__ XJ = C.A + (size_t)R_XJ * C.CB;
  const float* __restrict__ F = C.F;
  float acc[25];
#pragma unroll
  for (int c = 0; c < 25; ++c) acc[c] = 0.f;
  for (int k = 0; k < 250; ++k) {
    int o = k >> 1, dh = k & 1;
    float xv = bf2f(XJ[(size_t)((o * 3 + hh + dh) * 10 + q) * C.CB + col]);
    const float* __restrict__ w = F + OF_CA2T + k * 25;
#pragma unroll
    for (int c = 0; c < 25; ++c) acc[c] += w[c] * xv;
  }
  float s02 = F[OF_CS02 + q];
  float part = 0.f;
#pragma unroll
  for (int c = 0; c < 25; ++c) {
    float zc = fmaxf(acc[c] + C.ca2_b[c] * s02 + C.l02_b[q], 0.f);
    part += C.cb2_w[c * 2 + hh] * zc;
  }
  atomicAdd(&C.zAcc[col], C.fl_w[q] * part);
}

// ---------- K8c: out = const + zAcc + yAcc[h]. grid (CB/256, 1) ----------
__global__ __launch_bounds__(256) void k8c(Ctx C) {
  const int col = blockIdx.x * 256 + threadIdx.x;
  if (col >= C.CB) return;
  float scc2 = C.F[OF_CSCC2];
  float cst = C.fl_b[0];
#pragma unroll
  for (int q = 0; q < 10; ++q)
    cst += C.fl_w[q] * (C.cb2_b[0] + C.r02_b[q] * scc2 + C.cc2_b[0]);
  float za = C.zAcc[col];
#pragma unroll
  for (int h = 0; h < 3; ++h)
    C.out[(size_t)(C.b0g + col) * 3 + h] = cst + za + C.yAcc[(size_t)h * C.CB + col];
}

extern "C" void kernel_launch(void* const* d_in, const int* in_sizes, int n_in,
                              void* d_out, int out_size, void* d_ws, size_t ws_size,
                              hipStream_t stream) {
  (void)n_in; (void)out_size;
  Ctx C;
  C.x     = (const float*)d_in[0];
  C.ca1_w = (const float*)d_in[1];  C.ca1_b = (const float*)d_in[2];
  C.l01_w = (const float*)d_in[3];  C.l01_b = (const float*)d_in[4];
  C.cb1_w = (const float*)d_in[5];  C.cb1_b = (const float*)d_in[6];
  C.cc1_w = (const float*)d_in[7];  C.cc1_b = (const float*)d_in[8];
  C.r01_w = (const float*)d_in[9];  C.r01_b = (const float*)d_in[10];
  C.c1_w  = (const float*)d_in[11]; C.c1_b  = (const float*)d_in[12];
  C.l1_w  = (const float*)d_in[13]; C.l1_b  = (const float*)d_in[14];
  C.c2_w  = (const float*)d_in[15]; C.c2_b  = (const float*)d_in[16];
  C.ca_w  = (const float*)d_in[17]; C.ca_b  = (const float*)d_in[18];
  C.ra_w  = (const float*)d_in[19]; C.ra_b  = (const float*)d_in[20];
  C.ca2_w = (const float*)d_in[21]; C.ca2_b = (const float*)d_in[22];
  C.l02_w = (const float*)d_in[23]; C.l02_b = (const float*)d_in[24];
  C.cb2_w = (const float*)d_in[25]; C.cb2_b = (const float*)d_in[26];
  C.cc2_w = (const float*)d_in[27]; C.cc2_b = (const float*)d_in[28];
  C.r02_w = (const float*)d_in[29]; C.r02_b = (const float*)d_in[30];
  C.fl_w  = (const float*)d_in[31]; C.fl_b  = (const float*)d_in[32];
  C.out   = (float*)d_out;

  const int B = in_sizes[0] / 635;

  int CB = 4096;
  if (CB > B) CB = B;
  size_t accoff, actoff;
  for (;;) {
    accoff = ((size_t)F32_TOTAL * 4 + 255) & ~(size_t)255;
    actoff = (accoff + (size_t)4 * CB * 4 + 255) & ~(size_t)255;
    if (CB <= 256 || actoff + (size_t)ROWS_TOTAL * CB * 2 <= ws_size) break;
    CB >>= 1;
  }
  C.F = (float*)d_ws;
  C.zAcc = (float*)((char*)d_ws + accoff);
  C.yAcc = C.zAcc + CB;
  C.A = (u16*)((char*)d_ws + actoff);
  C.CB = CB;

  C.b0g = 0;
  k0c<<<dim3(32), dim3(256), 0, stream>>>(C);

  const int bt64 = CB / 64, bt256 = (CB + 255) / 256;
  for (int b0 = 0; b0 < B; b0 += CB) {
    C.b0g = b0;
    hipMemsetAsync(C.zAcc, 0, (size_t)4 * CB * sizeof(float), stream);
    k0t<<<dim3(bt64, 10),   dim3(256), 0, stream>>>(C);
    k1 <<<dim3(bt256, 30),  dim3(256), 0, stream>>>(C);
    k2 <<<dim3(bt256, 75),  dim3(256), 0, stream>>>(C);
    k3 <<<dim3(bt256, 60),  dim3(256), 0, stream>>>(C);
    k4 <<<dim3(bt256, 300), dim3(256), 0, stream>>>(C);
    k5 <<<dim3(bt256, 150), dim3(256), 0, stream>>>(C);
    k6t<0><<<dim3(bt256, 60), dim3(256), 0, stream>>>(C);
    k6t<1><<<dim3(bt256, 60), dim3(256), 0, stream>>>(C);
    k6t<2><<<dim3(bt256, 60), dim3(256), 0, stream>>>(C);
    k7 <<<dim3(bt256, 375), dim3(256), 0, stream>>>(C);
    k8a<<<dim3(bt256, 20),  dim3(256), 0, stream>>>(C);
    k8c<<<dim3(bt256, 1),   dim3(256), 0, stream>>>(C);
  }
}